// Round 11
// baseline (232.154 us; speedup 1.0000x reference)
//
#include <hip/hip_runtime.h>

typedef unsigned short u16;
using f32x4  = __attribute__((ext_vector_type(4))) float;
using bf16x8 = __attribute__((ext_vector_type(8))) short;

#define SEQ 4096
#define HS  1024
#define NHEAD 16
#define DH  64

__device__ __forceinline__ u16 f2bf(float f) {
  unsigned u = __float_as_uint(f);
  unsigned r = (u + 0x7fffu + ((u >> 16) & 1u)) >> 16;
  return (u16)r;
}

__device__ __forceinline__ void gl_lds16(const void* g, void* l) {
  __builtin_amdgcn_global_load_lds(
      (const __attribute__((address_space(1))) unsigned int*)g,
      (__attribute__((address_space(3))) unsigned int*)l, 16, 0, 0);
}

#define LGKM0 asm volatile("s_waitcnt lgkmcnt(0)" ::: "memory")
#define BARR  __builtin_amdgcn_s_barrier()

// ---------------- fp32 -> bf16 conversion (X | Wq | Wk | Wv fused; dst contiguous) ----------------
__global__ void cvt_all(const float* __restrict__ X, const float* __restrict__ Wq,
                        const float* __restrict__ Wk, const float* __restrict__ Wv,
                        u16* __restrict__ dst) {
  const int N = 19922944;  // 16777216 + 3*1048576
  int idx = blockIdx.x * blockDim.x + threadIdx.x;
  int stride = gridDim.x * blockDim.x;
  for (int i = idx * 4; i < N; i += stride * 4) {
    const float* s;
    if (i < 16777216)       s = X  + i;
    else if (i < 17825792)  s = Wq + (i - 16777216);
    else if (i < 18874368)  s = Wk + (i - 17825792);
    else                    s = Wv + (i - 18874368);
    float4 v = *reinterpret_cast<const float4*>(s);
    u16 o0 = f2bf(v.x), o1 = f2bf(v.y), o2 = f2bf(v.z), o3 = f2bf(v.w);
    unsigned lo = (unsigned)o0 | ((unsigned)o1 << 16);
    unsigned hi = (unsigned)o2 | ((unsigned)o3 << 16);
    uint2 pk; pk.x = lo; pk.y = hi;
    *reinterpret_cast<uint2*>(dst + i) = pk;
  }
}

// ---------------- fused QKV projection GEMM: 256x256 tile, 2 super-phases/K-tile ----------------
// C[m,n] = sum_k X[m,k]*W[n,k] + bias[n];  M=16384, K=1024, logical N=3072 (Q|K|V).
// Grid 768 blocks. XCD-supertile map keeps X slice + W window L2-hot (FETCH 74MB).
// 128KB LDS double-buffer. Same staging layout + read addressing as the R4-proven kernel
// (conflicts 0); only change vs R10: 4 phases -> 2 super-phases (32 MFMA each), halving
// barrier/lgkm overhead. Every stage is consumed exactly 2 super-phases after issue;
// vmcnt(4) per super-phase preserves the R4 safety invariant.
// DO NOT: min-waves launch_bounds (R5 spill), 64KB single-buffer (R6 spill),
// 32x32x16 MFMA with this layout (R8 conflicts).
__global__ __launch_bounds__(512) void gemm_qkv8(
    const u16* __restrict__ X,
    const u16* __restrict__ Wq, const u16* __restrict__ Wk, const u16* __restrict__ Wv,
    const float* __restrict__ bq, const float* __restrict__ bk, const float* __restrict__ bv,
    u16* __restrict__ Q, u16* __restrict__ K, u16* __restrict__ V) {
  __shared__ u16 lds[65536];  // 128 KiB

  const int tid = threadIdx.x;
  const int l = tid & 63;
  const int w = tid >> 6;       // 0..7
  const int wr = w >> 2;        // 0..1  (m)
  const int wc = w & 3;         // 0..3  (n)
  const int c = l & 15;
  const int g = l >> 4;

  // block decode: i -> (xcd, window, n-in-window, m-in-xcd)
  int i = blockIdx.x;
  int k8 = i & 7, j8 = i >> 3;
  int w2 = j8 >> 5, r8 = j8 & 31;
  int np = w2 * 4 + (r8 >> 3);     // 0..11
  int mp = k8 * 8 + (r8 & 7);      // 0..63
  const int m0 = mp * 256;
  const int mat = np >> 2;
  const int n0 = (np & 3) * 256;
  const u16* W = (mat == 0) ? Wq : (mat == 1) ? Wk : Wv;
  const float* bias = (mat == 0) ? bq : (mat == 1) ? bk : bv;
  u16* O = (mat == 0) ? Q : (mat == 1) ? K : V;

  f32x4 acc[2][4][4] = {};

  auto stage = [&](const u16* G, int gbase, int ktile, int kh, int which) {
    u16* region = lds + ((ktile & 1) * 32768 + which * 16384 + kh * 8192);
#pragma unroll
    for (int ii = 0; ii < 2; ++ii) {
      int chunk = w * 2 + ii;
      int srow = chunk * 8 + (l >> 3);
      int slot = (l & 7) ^ (l >> 3);
      int grow = srow + ((slot >> 2) << 7);
      int ke = ktile * 64 + kh * 32 + (slot & 3) * 8;
      gl_lds16(G + (size_t)(gbase + grow) * HS + ke, region + chunk * 512);
    }
  };

  // reads: byte-identical addressing to the R4-proven kernel (conflict-free)
  auto readA = [&](int cur, int KH, bf16x8 (*aq)[4]) {
    const char* base = (const char*)lds + cur * 65536 + KH * 16384;
    int colb = (wr * 64 + g * 16) ^ ((c & 7) << 4);
#pragma unroll
    for (int CH = 0; CH < 2; ++CH)
#pragma unroll
      for (int mf = 0; mf < 4; ++mf)
        aq[CH][mf] = *reinterpret_cast<const bf16x8*>(base + (CH * 64 + mf * 16 + c) * 128 + colb);
  };
  auto readB = [&](int cur, int KH, bf16x8* bq2) {
    const char* base = (const char*)lds + cur * 65536 + 32768 + KH * 16384;
    int colb = ((wc >> 1) * 64 + g * 16) ^ ((c & 7) << 4);
#pragma unroll
    for (int nf = 0; nf < 4; ++nf)
      bq2[nf] = *reinterpret_cast<const bf16x8*>(base + ((wc & 1) * 64 + nf * 16 + c) * 128 + colb);
  };
  auto mma32 = [&](bf16x8 (*aq)[4], bf16x8* bq2) {
    __builtin_amdgcn_s_setprio(1);
#pragma unroll
    for (int CH = 0; CH < 2; ++CH)
#pragma unroll
      for (int mf = 0; mf < 4; ++mf)
#pragma unroll
        for (int nf = 0; nf < 4; ++nf)
          acc[CH][mf][nf] = __builtin_amdgcn_mfma_f32_16x16x32_bf16(aq[CH][mf], bq2[nf], acc[CH][mf][nf], 0, 0, 0);
    __builtin_amdgcn_s_setprio(0);
  };

  // prologue: t0 fully + t1 kh0 halves; drain t0-resident (leave t1kh0's 4 in flight)
  stage(X, m0, 0, 0, 0); stage(W, n0, 0, 0, 1);
  stage(X, m0, 0, 1, 0); stage(W, n0, 0, 1, 1);
  stage(X, m0, 1, 0, 0); stage(W, n0, 1, 0, 1);
  asm volatile("s_waitcnt vmcnt(4)" ::: "memory");
  BARR;

  for (int j = 0; j < 16; ++j) {
    const int cur = j & 1;
    bf16x8 aq[2][4], bq2[4];
    // S0 (kh0): read all A/B kh0; stage t_{j+1}.kh1 (opposite buf; dead since S1(j-1))
    readA(cur, 0, aq); readB(cur, 0, bq2);
    if (j + 1 < 16) { stage(X, m0, j + 1, 1, 0); stage(W, n0, j + 1, 1, 1); }
    BARR; LGKM0; mma32(aq, bq2);
    asm volatile("s_waitcnt vmcnt(4)" ::: "memory");  // retire stages issued 2 phases ago
    BARR;
    // S1 (kh1): read all A/B kh1; stage t_{j+2}.kh0 (current buf kh0; dead since S0(j))
    readA(cur, 1, aq); readB(cur, 1, bq2);
    if (j + 2 < 16) { stage(X, m0, j + 2, 0, 0); stage(W, n0, j + 2, 0, 1); }
    BARR; LGKM0; mma32(aq, bq2);
    if (j < 14)       asm volatile("s_waitcnt vmcnt(4)" ::: "memory");
    else if (j == 14) asm volatile("s_waitcnt vmcnt(0)" ::: "memory");
    BARR;
  }

  // ---- epilogue: LDS-staged full-line stores, two passes of 128 rows ----
  __syncthreads();
  {
    u16* cst = lds;  // [128][260] u16 per pass
#pragma unroll 1
    for (int p = 0; p < 2; ++p) {
      if (wr == p) {
#pragma unroll
        for (int nf = 0; nf < 4; ++nf) {
          int cc = wc * 64 + nf * 16 + c;
          float bval = bias[n0 + cc];
#pragma unroll
          for (int ch = 0; ch < 2; ++ch)
#pragma unroll
            for (int mf = 0; mf < 4; ++mf)
#pragma unroll
              for (int jj = 0; jj < 4; ++jj) {
                int rl = ch * 64 + mf * 16 + g * 4 + jj;
                cst[rl * 260 + cc] = f2bf(acc[ch][mf][nf][jj] + bval);
              }
        }
      }
      __syncthreads();
#pragma unroll
      for (int i2 = 0; i2 < 8; ++i2) {
        int row = i2 * 16 + (tid >> 5);
        int colu = (tid & 31) * 8;
        bf16x8 vv = *reinterpret_cast<const bf16x8*>(cst + row * 260 + colu);
        *reinterpret_cast<bf16x8*>(O + (size_t)(m0 + p * 128 + row) * HS + n0 + colu) = vv;
      }
      __syncthreads();
    }
  }
}

// ---------------- BigBird block-sparse attention (load-balanced, L2-local) ----------------
// 4992 blocks = 8 XCDs x 624; XCD x owns (b,h) in {8x..8x+7}, 78 blocks per (b,h).
// Per (b,h): r 0..61 -> main qb=r+1 (4-5 kb); r 62..77 -> 16 heavy segs (8 kb each) of qb 0/63.
__global__ void bigbird_attn2(const u16* __restrict__ Q, const u16* __restrict__ K,
                              const u16* __restrict__ V, float* __restrict__ OUT,
                              float* __restrict__ Opart, float* __restrict__ MLpart) {
  __shared__ u16 Qs[64 * 64];
  __shared__ u16 Ks[2][64 * 64];
  __shared__ u16 Vt[64 * 72];
  __shared__ u16 Ps[64 * 72];

  const int tid = threadIdx.x;
  const int lane = tid & 63;
  const int w = tid >> 6;
  const int g = lane >> 4;
  const int c = lane & 15;

  int bid = blockIdx.x;
  int L = (bid & 7) * 624 + (bid >> 3);   // XCD-chunked bijection (4992 = 8*624)
  int g_bh = L / 78;
  int r = L - g_bh * 78;
  int b = g_bh & 3, h = g_bh >> 2;

  int qb, nkb, seg8 = 0, p = 0;
  bool heavy;
  if (r < 62) {
    heavy = false;
    qb = r + 1;
    nkb = (qb == 1 || qb == 62) ? 4 : 5;
  } else {
    heavy = true;
    int s = r - 62;               // 0..15
    int q2 = s >> 3, seg = s & 7;
    qb = q2 ? 63 : 0; seg8 = seg * 8; nkb = 8;
    p = ((q2 * 16 + h) * 4 + b) * 8 + seg;
  }

  const size_t base_bh = (size_t)b * SEQ * HS + (size_t)h * DH;

  auto kb_of = [&](int it) -> int {
    if (heavy) return seg8 + it;
    if (qb == 1)  return (it == 3) ? 63 : it;
    if (qb == 62) return (it == 0) ? 0 : 60 + it;
    return (it == 0) ? 0 : ((it == 4) ? 63 : qb - 2 + it);
  };

  {
    const u16* qg = Q + base_bh + (size_t)qb * 64 * HS;
#pragma unroll
    for (int t2 = 0; t2 < 2; ++t2) {
      int sub = w * 2 + t2;
      int rr = sub * 8 + (lane >> 3);
      int c16 = (lane & 7) ^ (rr & 7);
      gl_lds16(qg + (size_t)rr * HS + c16 * 8, Qs + sub * 512);
    }
  }
  int kb0 = kb_of(0);
  {
    const u16* kg = K + base_bh + (size_t)kb0 * 64 * HS;
#pragma unroll
    for (int t2 = 0; t2 < 2; ++t2) {
      int sub = w * 2 + t2;
      int rr = sub * 8 + (lane >> 3);
      int c16 = (lane & 7) ^ (rr & 7);
      gl_lds16(kg + (size_t)rr * HS + c16 * 8, Ks[0] + sub * 512);
    }
  }
  bf16x8 vr0, vr1;
  {
    const u16* vg = V + base_bh + (size_t)kb0 * 64 * HS;
    int krow = tid >> 2, dseg = (tid & 3) * 16;
    vr0 = *reinterpret_cast<const bf16x8*>(vg + (size_t)krow * HS + dseg);
    vr1 = *reinterpret_cast<const bf16x8*>(vg + (size_t)krow * HS + dseg + 8);
  }
  __syncthreads();

  bf16x8 qf[2];
#pragma unroll
  for (int ks = 0; ks < 2; ++ks) {
    int rr = w * 16 + c;
    int c16 = (ks * 4 + g) ^ (rr & 7);
    qf[ks] = *reinterpret_cast<const bf16x8*>(Qs + rr * 64 + c16 * 8);
  }

  float m_run = -1e30f, l_run = 0.f;
  f32x4 o_acc[4] = {};
  const float scale = 0.125f;

  for (int it = 0; it < nkb; ++it) {
    const int cur = it & 1;
    {
      int krow = tid >> 2, dseg = (tid & 3) * 16;
#pragma unroll
      for (int j2 = 0; j2 < 8; ++j2) {
        Vt[(dseg + j2) * 72 + krow]     = (u16)vr0[j2];
        Vt[(dseg + 8 + j2) * 72 + krow] = (u16)vr1[j2];
      }
    }
    if (it + 1 < nkb) {
      int kbn = kb_of(it + 1);
      const u16* kg = K + base_bh + (size_t)kbn * 64 * HS;
#pragma unroll
      for (int t2 = 0; t2 < 2; ++t2) {
        int sub = w * 2 + t2;
        int rr = sub * 8 + (lane >> 3);
        int c16 = (lane & 7) ^ (rr & 7);
        gl_lds16(kg + (size_t)rr * HS + c16 * 8, Ks[cur ^ 1] + sub * 512);
      }
      const u16* vg = V + base_bh + (size_t)kbn * 64 * HS;
      int krow = tid >> 2, dseg = (tid & 3) * 16;
      vr0 = *reinterpret_cast<const bf16x8*>(vg + (size_t)krow * HS + dseg);
      vr1 = *reinterpret_cast<const bf16x8*>(vg + (size_t)krow * HS + dseg + 8);
    }

    f32x4 accs[4] = {};
#pragma unroll
    for (int ks = 0; ks < 2; ++ks) {
#pragma unroll
      for (int mf = 0; mf < 4; ++mf) {
        int rr = mf * 16 + c;
        int c16 = (ks * 4 + g) ^ (rr & 7);
        bf16x8 kf = *reinterpret_cast<const bf16x8*>(Ks[cur] + rr * 64 + c16 * 8);
        accs[mf] = __builtin_amdgcn_mfma_f32_16x16x32_bf16(kf, qf[ks], accs[mf], 0, 0, 0);
      }
    }

    float sv[16];
    float smax = -1e30f;
#pragma unroll
    for (int mf = 0; mf < 4; ++mf)
#pragma unroll
      for (int j = 0; j < 4; ++j) {
        float s = accs[mf][j] * scale;
        sv[mf * 4 + j] = s;
        smax = fmaxf(smax, s);
      }
    smax = fmaxf(smax, __shfl_xor(smax, 16));
    smax = fmaxf(smax, __shfl_xor(smax, 32));
    float m_new = fmaxf(m_run, smax);
    float corr = __expf(m_run - m_new);
    float psum = 0.f;
    u16 pb[16];
#pragma unroll
    for (int i = 0; i < 16; ++i) {
      float pv = __expf(sv[i] - m_new);
      psum += pv;
      pb[i] = f2bf(pv);
    }
    psum += __shfl_xor(psum, 16);
    psum += __shfl_xor(psum, 32);
    l_run = l_run * corr + psum;
    m_run = m_new;

#pragma unroll
    for (int j = 0; j < 4; ++j) {
      float cj = __shfl(corr, g * 4 + j);
#pragma unroll
      for (int df = 0; df < 4; ++df) o_acc[df][j] *= cj;
    }

    {
      int rr = w * 16 + c;
#pragma unroll
      for (int mf = 0; mf < 4; ++mf) {
        unsigned lo = (unsigned)pb[mf * 4 + 0] | ((unsigned)pb[mf * 4 + 1] << 16);
        unsigned hi = (unsigned)pb[mf * 4 + 2] | ((unsigned)pb[mf * 4 + 3] << 16);
        uint2 pk; pk.x = lo; pk.y = hi;
        *reinterpret_cast<uint2*>(Ps + rr * 72 + mf * 16 + g * 4) = pk;
      }
    }

    __syncthreads();

#pragma unroll
    for (int ks = 0; ks < 2; ++ks) {
      bf16x8 pf = *reinterpret_cast<const bf16x8*>(Ps + (w * 16 + c) * 72 + ks * 32 + g * 8);
#pragma unroll
      for (int df = 0; df < 4; ++df) {
        bf16x8 vf = *reinterpret_cast<const bf16x8*>(Vt + (df * 16 + c) * 72 + ks * 32 + g * 8);
        o_acc[df] = __builtin_amdgcn_mfma_f32_16x16x32_bf16(pf, vf, o_acc[df], 0, 0, 0);
      }
    }

    __syncthreads();
  }

  if (!heavy) {
#pragma unroll
    for (int j = 0; j < 4; ++j) {
      float lr = __shfl(l_run, g * 4 + j);
      float inv = 1.f / lr;
      int rr = qb * 64 + w * 16 + g * 4 + j;
      size_t rowbase = ((size_t)b * SEQ + rr) * HS + (size_t)h * DH;
#pragma unroll
      for (int df = 0; df < 4; ++df)
        OUT[rowbase + df * 16 + c] = o_acc[df][j] * inv;
    }
  } else {
#pragma unroll
    for (int j = 0; j < 4; ++j) {
      int row = w * 16 + g * 4 + j;
#pragma unroll
      for (int df = 0; df < 4; ++df)
        Opart[(size_t)p * 4096 + row * 64 + df * 16 + c] = o_acc[df][j];
    }
    if (g == 0) {
      int row = w * 16 + c;
      MLpart[(size_t)p * 128 + row * 2]     = m_run;
      MLpart[(size_t)p * 128 + row * 2 + 1] = l_run;
    }
  }
}

// ---------------- combine partials for qb 0 / 63 (512 blocks, 8 segs) ----------------
__global__ void bigbird_combine(const float* __restrict__ Opart, const float* __restrict__ MLpart,
                                float* __restrict__ OUT) {
  int bid = blockIdx.x >> 2;          // 128 = (q2, h, b)
  int quarter = blockIdx.x & 3;       // 4 rows each
  int b = bid & 3; int t = bid >> 2; int h = t & 15; int q2 = t >> 4;
  int qb = q2 ? 63 : 0;
  int w = threadIdx.x >> 6, lane = threadIdx.x & 63;
  int pbase = ((q2 * 16 + h) * 4 + b) * 8;
#pragma unroll 1
  for (int j2 = 0; j2 < 4; ++j2) {
    int rr = quarter * 4 + j2;
    int row = w * 16 + rr;
    float ms[8], ls[8];
    float M = -1e30f;
#pragma unroll
    for (int s = 0; s < 8; ++s) {
      ms[s] = MLpart[(size_t)(pbase + s) * 128 + row * 2];
      ls[s] = MLpart[(size_t)(pbase + s) * 128 + row * 2 + 1];
      M = fmaxf(M, ms[s]);
    }
    float L = 0.f, acc = 0.f;
#pragma unroll
    for (int s = 0; s < 8; ++s) {
      float e = __expf(ms[s] - M);
      L += ls[s] * e;
      acc += e * Opart[(size_t)(pbase + s) * 4096 + row * 64 + lane];
    }
    int rq = qb * 64 + row;
    OUT[((size_t)b * SEQ + rq) * HS + (size_t)h * DH + lane] = acc / L;
  }
}

extern "C" void kernel_launch(void* const* d_in, const int* in_sizes, int n_in,
                              void* d_out, int out_size, void* d_ws, size_t ws_size,
                              hipStream_t stream) {
  const float* X  = (const float*)d_in[0];
  const float* Wq = (const float*)d_in[1];
  const float* bq = (const float*)d_in[2];
  const float* Wk = (const float*)d_in[3];
  const float* bk = (const float*)d_in[4];
  const float* Wv = (const float*)d_in[5];
  const float* bv = (const float*)d_in[6];
  float* out = (float*)d_out;

  u16* Xb  = (u16*)d_ws;
  u16* Wqb = Xb + 16777216;
  u16* Wkb = Wqb + 1048576;
  u16* Wvb = Wkb + 1048576;
  u16* Qb  = Wvb + 1048576;
  u16* Kb  = Qb + 16777216;
  u16* Vb  = Kb + 16777216;

  float* Opart  = (float*)Xb;    // 1024 * 4096 floats = 16.8 MB (aliases dead Xb)
  float* MLpart = (float*)Wqb;   // 1024 * 128 floats (aliases dead Wqb)

  cvt_all<<<2048, 256, 0, stream>>>(X, Wq, Wk, Wv, Xb);
  gemm_qkv8<<<768, 512, 0, stream>>>(Xb, Wqb, Wkb, Wvb, bq, bk, bv, Qb, Kb, Vb);
  bigbird_attn2<<<4992, 256, 0, stream>>>(Qb, Kb, Vb, out, Opart, MLpart);
  bigbird_combine<<<512, 256, 0, stream>>>(Opart, MLpart, out);
}

// Round 12
// 224.786 us; speedup vs baseline: 1.0328x; 1.0328x over previous
//
#include <hip/hip_runtime.h>

typedef unsigned short u16;
using f32x4  = __attribute__((ext_vector_type(4))) float;
using bf16x8 = __attribute__((ext_vector_type(8))) short;

#define SEQ 4096
#define HS  1024
#define NHEAD 16
#define DH  64

__device__ __forceinline__ u16 f2bf(float f) {
  unsigned u = __float_as_uint(f);
  unsigned r = (u + 0x7fffu + ((u >> 16) & 1u)) >> 16;
  return (u16)r;
}

__device__ __forceinline__ void gl_lds16(const void* g, void* l) {
  __builtin_amdgcn_global_load_lds(
      (const __attribute__((address_space(1))) unsigned int*)g,
      (__attribute__((address_space(3))) unsigned int*)l, 16, 0, 0);
}

#define LGKM0 asm volatile("s_waitcnt lgkmcnt(0)" ::: "memory")
#define BARR  __builtin_amdgcn_s_barrier()

// ---------------- fp32 -> bf16 conversion (X | Wq | Wk | Wv fused; dst contiguous) ----------------
__global__ void cvt_all(const float* __restrict__ X, const float* __restrict__ Wq,
                        const float* __restrict__ Wk, const float* __restrict__ Wv,
                        u16* __restrict__ dst) {
  const int N = 19922944;  // 16777216 + 3*1048576
  int idx = blockIdx.x * blockDim.x + threadIdx.x;
  int stride = gridDim.x * blockDim.x;
  for (int i = idx * 4; i < N; i += stride * 4) {
    const float* s;
    if (i < 16777216)       s = X  + i;
    else if (i < 17825792)  s = Wq + (i - 16777216);
    else if (i < 18874368)  s = Wk + (i - 17825792);
    else                    s = Wv + (i - 18874368);
    float4 v = *reinterpret_cast<const float4*>(s);
    u16 o0 = f2bf(v.x), o1 = f2bf(v.y), o2 = f2bf(v.z), o3 = f2bf(v.w);
    unsigned lo = (unsigned)o0 | ((unsigned)o1 << 16);
    unsigned hi = (unsigned)o2 | ((unsigned)o3 << 16);
    uint2 pk; pk.x = lo; pk.y = hi;
    *reinterpret_cast<uint2*>(dst + i) = pk;
  }
}

// ---------------- fused QKV projection GEMM: 256x256 tile, 8-phase (R4/R10-proven) ----------------
// PROVEN 126.7us / MfmaUtil 34% / conflicts 0 / FETCH 74MB.
// DO NOT: min-waves launch_bounds (R5 spill), 64KB single-buffer (R6 spill),
// 32x32x16 MFMA with this layout (R8 conflicts), 2-super-phase merge (R11 neutral).
__global__ __launch_bounds__(512) void gemm_qkv8(
    const u16* __restrict__ X,
    const u16* __restrict__ Wq, const u16* __restrict__ Wk, const u16* __restrict__ Wv,
    const float* __restrict__ bq, const float* __restrict__ bk, const float* __restrict__ bv,
    u16* __restrict__ Q, u16* __restrict__ K, u16* __restrict__ V) {
  __shared__ u16 lds[65536];  // 128 KiB

  const int tid = threadIdx.x;
  const int l = tid & 63;
  const int w = tid >> 6;       // 0..7
  const int wr = w >> 2;        // 0..1  (m)
  const int wc = w & 3;         // 0..3  (n)
  const int c = l & 15;
  const int g = l >> 4;

  // block decode: i -> (xcd, window, n-in-window, m-in-xcd)
  int i = blockIdx.x;
  int k8 = i & 7, j8 = i >> 3;
  int w2 = j8 >> 5, r8 = j8 & 31;
  int np = w2 * 4 + (r8 >> 3);     // 0..11
  int mp = k8 * 8 + (r8 & 7);      // 0..63
  const int m0 = mp * 256;
  const int mat = np >> 2;
  const int n0 = (np & 3) * 256;
  const u16* W = (mat == 0) ? Wq : (mat == 1) ? Wk : Wv;
  const float* bias = (mat == 0) ? bq : (mat == 1) ? bk : bv;
  u16* O = (mat == 0) ? Q : (mat == 1) ? K : V;

  f32x4 acc[2][4][4] = {};

  auto stage = [&](const u16* G, int gbase, int ktile, int kh, int which) {
    u16* region = lds + ((ktile & 1) * 32768 + which * 16384 + kh * 8192);
#pragma unroll
    for (int ii = 0; ii < 2; ++ii) {
      int chunk = w * 2 + ii;
      int srow = chunk * 8 + (l >> 3);
      int slot = (l & 7) ^ (l >> 3);
      int grow = srow + ((slot >> 2) << 7);
      int ke = ktile * 64 + kh * 32 + (slot & 3) * 8;
      gl_lds16(G + (size_t)(gbase + grow) * HS + ke, region + chunk * 512);
    }
  };

  auto readA = [&](int cur, int CH, int KH, bf16x8* aq) {
    const char* base = (const char*)lds + cur * 65536 + KH * 16384;
    int colb = (wr * 64 + g * 16) ^ ((c & 7) << 4);
#pragma unroll
    for (int mf = 0; mf < 4; ++mf)
      aq[mf] = *reinterpret_cast<const bf16x8*>(base + (CH * 64 + mf * 16 + c) * 128 + colb);
  };
  auto readB = [&](int cur, int KH, bf16x8* bq2) {
    const char* base = (const char*)lds + cur * 65536 + 32768 + KH * 16384;
    int colb = ((wc >> 1) * 64 + g * 16) ^ ((c & 7) << 4);
#pragma unroll
    for (int nf = 0; nf < 4; ++nf)
      bq2[nf] = *reinterpret_cast<const bf16x8*>(base + ((wc & 1) * 64 + nf * 16 + c) * 128 + colb);
  };
  auto mma16 = [&](bf16x8* aq, bf16x8* bq2, f32x4 (*accr)[4]) {
    __builtin_amdgcn_s_setprio(1);
#pragma unroll
    for (int mf = 0; mf < 4; ++mf)
#pragma unroll
      for (int nf = 0; nf < 4; ++nf)
        accr[mf][nf] = __builtin_amdgcn_mfma_f32_16x16x32_bf16(aq[mf], bq2[nf], accr[mf][nf], 0, 0, 0);
    __builtin_amdgcn_s_setprio(0);
  };

  // prologue: t0 fully + t1 kh0 halves; drain to t0-resident
  stage(X, m0, 0, 0, 0); stage(W, n0, 0, 0, 1);
  stage(X, m0, 0, 1, 0); stage(W, n0, 0, 1, 1);
  stage(X, m0, 1, 0, 0); stage(W, n0, 1, 0, 1);
  asm volatile("s_waitcnt vmcnt(4)" ::: "memory");
  BARR;

  for (int j = 0; j < 16; ++j) {
    const int cur = j & 1;
    bf16x8 aq[4], bq2[4];
    // ph0: (ch0, kh0) — stage t_{j+1}.A.k1 (opposite buf)
    readA(cur, 0, 0, aq); readB(cur, 0, bq2);
    if (j + 1 < 16) stage(X, m0, j + 1, 1, 0);
    BARR; LGKM0; mma16(aq, bq2, acc[0]); BARR;
    // ph1: (ch1, kh0) — stage t_{j+1}.B.k1
    readA(cur, 1, 0, aq);
    if (j + 1 < 16) stage(W, n0, j + 1, 1, 1);
    BARR; LGKM0; mma16(aq, bq2, acc[1]); BARR;
    // ph2: (ch0, kh1) — stage t_{j+2}.A.k0 (same buf; Ak0 dead since ph1)
    readA(cur, 0, 1, aq); readB(cur, 1, bq2);
    if (j + 2 < 16) stage(X, m0, j + 2, 0, 0);
    BARR; LGKM0; mma16(aq, bq2, acc[0]); BARR;
    // ph3: (ch1, kh1) — stage t_{j+2}.B.k0
    readA(cur, 1, 1, aq);
    if (j + 2 < 16) stage(W, n0, j + 2, 0, 1);
    BARR; LGKM0; mma16(aq, bq2, acc[1]);
    if (j < 14)       asm volatile("s_waitcnt vmcnt(4)" ::: "memory");
    else if (j == 14) asm volatile("s_waitcnt vmcnt(0)" ::: "memory");
    BARR;
  }

  // ---- epilogue: LDS-staged full-line stores, two passes of 128 rows ----
  __syncthreads();
  {
    u16* cst = lds;  // [128][260] u16 per pass
#pragma unroll 1
    for (int p = 0; p < 2; ++p) {
      if (wr == p) {
#pragma unroll
        for (int nf = 0; nf < 4; ++nf) {
          int cc = wc * 64 + nf * 16 + c;
          float bval = bias[n0 + cc];
#pragma unroll
          for (int ch = 0; ch < 2; ++ch)
#pragma unroll
            for (int mf = 0; mf < 4; ++mf)
#pragma unroll
              for (int jj = 0; jj < 4; ++jj) {
                int rl = ch * 64 + mf * 16 + g * 4 + jj;
                cst[rl * 260 + cc] = f2bf(acc[ch][mf][nf][jj] + bval);
              }
        }
      }
      __syncthreads();
#pragma unroll
      for (int i2 = 0; i2 < 8; ++i2) {
        int row = i2 * 16 + (tid >> 5);
        int colu = (tid & 31) * 8;
        bf16x8 vv = *reinterpret_cast<const bf16x8*>(cst + row * 260 + colu);
        *reinterpret_cast<bf16x8*>(O + (size_t)(m0 + p * 128 + row) * HS + n0 + colu) = vv;
      }
      __syncthreads();
    }
  }
}

// ---------------- BigBird block-sparse attention (load-balanced, L2-local) ----------------
// 4992 blocks = 8 XCDs x 624; XCD x owns (b,h) in {8x..8x+7}, 78 blocks per (b,h).
// Per (b,h): r 0..61 -> main qb=r+1 (4-5 kb); r 62..77 -> 16 heavy segs (8 kb each) of qb 0/63.
// V-scatter thread mapping: krow = tid&63, dseg = (tid>>6)*16 -> store bank = const + lane/2
// (32 banks x 2 same-dword lanes = free). Old mapping (krow=tid>>2) put 16 lanes on 2 banks
// (8-way conflict, 1.7e7 cycles/dispatch).
__global__ void bigbird_attn2(const u16* __restrict__ Q, const u16* __restrict__ K,
                              const u16* __restrict__ V, float* __restrict__ OUT,
                              float* __restrict__ Opart, float* __restrict__ MLpart) {
  __shared__ u16 Qs[64 * 64];
  __shared__ u16 Ks[2][64 * 64];
  __shared__ u16 Vt[64 * 72];
  __shared__ u16 Ps[64 * 72];

  const int tid = threadIdx.x;
  const int lane = tid & 63;
  const int w = tid >> 6;
  const int g = lane >> 4;
  const int c = lane & 15;

  int bid = blockIdx.x;
  int L = (bid & 7) * 624 + (bid >> 3);   // XCD-chunked bijection (4992 = 8*624)
  int g_bh = L / 78;
  int r = L - g_bh * 78;
  int b = g_bh & 3, h = g_bh >> 2;

  int qb, nkb, seg8 = 0, p = 0;
  bool heavy;
  if (r < 62) {
    heavy = false;
    qb = r + 1;
    nkb = (qb == 1 || qb == 62) ? 4 : 5;
  } else {
    heavy = true;
    int s = r - 62;               // 0..15
    int q2 = s >> 3, seg = s & 7;
    qb = q2 ? 63 : 0; seg8 = seg * 8; nkb = 8;
    p = ((q2 * 16 + h) * 4 + b) * 8 + seg;
  }

  const size_t base_bh = (size_t)b * SEQ * HS + (size_t)h * DH;

  auto kb_of = [&](int it) -> int {
    if (heavy) return seg8 + it;
    if (qb == 1)  return (it == 3) ? 63 : it;
    if (qb == 62) return (it == 0) ? 0 : 60 + it;
    return (it == 0) ? 0 : ((it == 4) ? 63 : qb - 2 + it);
  };

  const int vkrow = tid & 63;          // V-transpose role: lane = k-row
  const int vdseg = (tid >> 6) * 16;   // wave = d-segment

  {
    const u16* qg = Q + base_bh + (size_t)qb * 64 * HS;
#pragma unroll
    for (int t2 = 0; t2 < 2; ++t2) {
      int sub = w * 2 + t2;
      int rr = sub * 8 + (lane >> 3);
      int c16 = (lane & 7) ^ (rr & 7);
      gl_lds16(qg + (size_t)rr * HS + c16 * 8, Qs + sub * 512);
    }
  }
  int kb0 = kb_of(0);
  {
    const u16* kg = K + base_bh + (size_t)kb0 * 64 * HS;
#pragma unroll
    for (int t2 = 0; t2 < 2; ++t2) {
      int sub = w * 2 + t2;
      int rr = sub * 8 + (lane >> 3);
      int c16 = (lane & 7) ^ (rr & 7);
      gl_lds16(kg + (size_t)rr * HS + c16 * 8, Ks[0] + sub * 512);
    }
  }
  bf16x8 vr0, vr1;
  {
    const u16* vg = V + base_bh + (size_t)kb0 * 64 * HS;
    vr0 = *reinterpret_cast<const bf16x8*>(vg + (size_t)vkrow * HS + vdseg);
    vr1 = *reinterpret_cast<const bf16x8*>(vg + (size_t)vkrow * HS + vdseg + 8);
  }
  __syncthreads();

  bf16x8 qf[2];
#pragma unroll
  for (int ks = 0; ks < 2; ++ks) {
    int rr = w * 16 + c;
    int c16 = (ks * 4 + g) ^ (rr & 7);
    qf[ks] = *reinterpret_cast<const bf16x8*>(Qs + rr * 64 + c16 * 8);
  }

  float m_run = -1e30f, l_run = 0.f;
  f32x4 o_acc[4] = {};
  const float scale = 0.125f;

  for (int it = 0; it < nkb; ++it) {
    const int cur = it & 1;
    {
#pragma unroll
      for (int j2 = 0; j2 < 8; ++j2) {
        Vt[(vdseg + j2) * 72 + vkrow]     = (u16)vr0[j2];
        Vt[(vdseg + 8 + j2) * 72 + vkrow] = (u16)vr1[j2];
      }
    }
    if (it + 1 < nkb) {
      int kbn = kb_of(it + 1);
      const u16* kg = K + base_bh + (size_t)kbn * 64 * HS;
#pragma unroll
      for (int t2 = 0; t2 < 2; ++t2) {
        int sub = w * 2 + t2;
        int rr = sub * 8 + (lane >> 3);
        int c16 = (lane & 7) ^ (rr & 7);
        gl_lds16(kg + (size_t)rr * HS + c16 * 8, Ks[cur ^ 1] + sub * 512);
      }
      const u16* vg = V + base_bh + (size_t)kbn * 64 * HS;
      vr0 = *reinterpret_cast<const bf16x8*>(vg + (size_t)vkrow * HS + vdseg);
      vr1 = *reinterpret_cast<const bf16x8*>(vg + (size_t)vkrow * HS + vdseg + 8);
    }

    f32x4 accs[4] = {};
#pragma unroll
    for (int ks = 0; ks < 2; ++ks) {
#pragma unroll
      for (int mf = 0; mf < 4; ++mf) {
        int rr = mf * 16 + c;
        int c16 = (ks * 4 + g) ^ (rr & 7);
        bf16x8 kf = *reinterpret_cast<const bf16x8*>(Ks[cur] + rr * 64 + c16 * 8);
        accs[mf] = __builtin_amdgcn_mfma_f32_16x16x32_bf16(kf, qf[ks], accs[mf], 0, 0, 0);
      }
    }

    float sv[16];
    float smax = -1e30f;
#pragma unroll
    for (int mf = 0; mf < 4; ++mf)
#pragma unroll
      for (int j = 0; j < 4; ++j) {
        float s = accs[mf][j] * scale;
        sv[mf * 4 + j] = s;
        smax = fmaxf(smax, s);
      }
    smax = fmaxf(smax, __shfl_xor(smax, 16));
    smax = fmaxf(smax, __shfl_xor(smax, 32));
    float m_new = fmaxf(m_run, smax);
    float corr = __expf(m_run - m_new);
    float psum = 0.f;
    u16 pb[16];
#pragma unroll
    for (int i = 0; i < 16; ++i) {
      float pv = __expf(sv[i] - m_new);
      psum += pv;
      pb[i] = f2bf(pv);
    }
    psum += __shfl_xor(psum, 16);
    psum += __shfl_xor(psum, 32);
    l_run = l_run * corr + psum;
    m_run = m_new;

#pragma unroll
    for (int j = 0; j < 4; ++j) {
      float cj = __shfl(corr, g * 4 + j);
#pragma unroll
      for (int df = 0; df < 4; ++df) o_acc[df][j] *= cj;
    }

    {
      int rr = w * 16 + c;
#pragma unroll
      for (int mf = 0; mf < 4; ++mf) {
        unsigned lo = (unsigned)pb[mf * 4 + 0] | ((unsigned)pb[mf * 4 + 1] << 16);
        unsigned hi = (unsigned)pb[mf * 4 + 2] | ((unsigned)pb[mf * 4 + 3] << 16);
        uint2 pk; pk.x = lo; pk.y = hi;
        *reinterpret_cast<uint2*>(Ps + rr * 72 + mf * 16 + g * 4) = pk;
      }
    }

    __syncthreads();

#pragma unroll
    for (int ks = 0; ks < 2; ++ks) {
      bf16x8 pf = *reinterpret_cast<const bf16x8*>(Ps + (w * 16 + c) * 72 + ks * 32 + g * 8);
#pragma unroll
      for (int df = 0; df < 4; ++df) {
        bf16x8 vf = *reinterpret_cast<const bf16x8*>(Vt + (df * 16 + c) * 72 + ks * 32 + g * 8);
        o_acc[df] = __builtin_amdgcn_mfma_f32_16x16x32_bf16(pf, vf, o_acc[df], 0, 0, 0);
      }
    }

    __syncthreads();
  }

  if (!heavy) {
#pragma unroll
    for (int j = 0; j < 4; ++j) {
      float lr = __shfl(l_run, g * 4 + j);
      float inv = 1.f / lr;
      int rr = qb * 64 + w * 16 + g * 4 + j;
      size_t rowbase = ((size_t)b * SEQ + rr) * HS + (size_t)h * DH;
#pragma unroll
      for (int df = 0; df < 4; ++df)
        OUT[rowbase + df * 16 + c] = o_acc[df][j] * inv;
    }
  } else {
#pragma unroll
    for (int j = 0; j < 4; ++j) {
      int row = w * 16 + g * 4 + j;
#pragma unroll
      for (int df = 0; df < 4; ++df)
        Opart[(size_t)p * 4096 + row * 64 + df * 16 + c] = o_acc[df][j];
    }
    if (g == 0) {
      int row = w * 16 + c;
      MLpart[(size_t)p * 128 + row * 2]     = m_run;
      MLpart[(size_t)p * 128 + row * 2 + 1] = l_run;
    }
  }
}

// ---------------- combine partials for qb 0 / 63 (512 blocks, 8 segs) ----------------
__global__ void bigbird_combine(const float* __restrict__ Opart, const float* __restrict__ MLpart,
                                float* __restrict__ OUT) {
  int bid = blockIdx.x >> 2;          // 128 = (q2, h, b)
  int quarter = blockIdx.x & 3;       // 4 rows each
  int b = bid & 3; int t = bid >> 2; int h = t & 15; int q2 = t >> 4;
  int qb = q2 ? 63 : 0;
  int w = threadIdx.x >> 6, lane = threadIdx.x & 63;
  int pbase = ((q2 * 16 + h) * 4 + b) * 8;
#pragma unroll 1
  for (int j2 = 0; j2 < 4; ++j2) {
    int rr = quarter * 4 + j2;
    int row = w * 16 + rr;
    float ms[8], ls[8];
    float M = -1e30f;
#pragma unroll
    for (int s = 0; s < 8; ++s) {
      ms[s] = MLpart[(size_t)(pbase + s) * 128 + row * 2];
      ls[s] = MLpart[(size_t)(pbase + s) * 128 + row * 2 + 1];
      M = fmaxf(M, ms[s]);
    }
    float L = 0.f, acc = 0.f;
#pragma unroll
    for (int s = 0; s < 8; ++s) {
      float e = __expf(ms[s] - M);
      L += ls[s] * e;
      acc += e * Opart[(size_t)(pbase + s) * 4096 + row * 64 + lane];
    }
    int rq = qb * 64 + row;
    OUT[((size_t)b * SEQ + rq) * HS + (size_t)h * DH + lane] = acc / L;
  }
}

extern "C" void kernel_launch(void* const* d_in, const int* in_sizes, int n_in,
                              void* d_out, int out_size, void* d_ws, size_t ws_size,
                              hipStream_t stream) {
  const float* X  = (const float*)d_in[0];
  const float* Wq = (const float*)d_in[1];
  const float* bq = (const float*)d_in[2];
  const float* Wk = (const float*)d_in[3];
  const float* bk = (const float*)d_in[4];
  const float* Wv = (const float*)d_in[5];
  const float* bv = (const float*)d_in[6];
  float* out = (float*)d_out;

  u16* Xb  = (u16*)d_ws;
  u16* Wqb = Xb + 16777216;
  u16* Wkb = Wqb + 1048576;
  u16* Wvb = Wkb + 1048576;
  u16* Qb  = Wvb + 1048576;
  u16* Kb  = Qb + 16777216;
  u16* Vb  = Kb + 16777216;

  float* Opart  = (float*)Xb;    // 1024 * 4096 floats = 16.8 MB (aliases dead Xb)
  float* MLpart = (float*)Wqb;   // 1024 * 128 floats (aliases dead Wqb)

  cvt_all<<<2048, 256, 0, stream>>>(X, Wq, Wk, Wv, Xb);
  gemm_qkv8<<<768, 512, 0, stream>>>(Xb, Wqb, Wkb, Wvb, bq, bk, bv, Qb, Kb, Vb);
  bigbird_attn2<<<4992, 256, 0, stream>>>(Qb, Kb, Vb, out, Opart, MLpart);
  bigbird_combine<<<512, 256, 0, stream>>>(Opart, MLpart, out);
}